// Round 16
// baseline (419.243 us; speedup 1.0000x reference)
//
#include <hip/hip_runtime.h>

#define B_SZ   2
#define S_LEN  2048
#define D_DIM  1024
#define V_DIM  32000
#define NTOK   (B_SZ * S_LEN)   // 4096
#define NCYC   8
#define NPLANES 256
#define EPS_F  1.1920929e-07f

typedef float  f32x4  __attribute__((ext_vector_type(4)));
typedef __bf16 bf16x8 __attribute__((ext_vector_type(8)));

__device__ __forceinline__ unsigned short f32_to_bf16(float f) {
    unsigned int u = __builtin_bit_cast(unsigned int, f);
    u += 0x7fffu + ((u >> 16) & 1u);   // round-to-nearest-even
    return (unsigned short)(u >> 16);
}

// ============ fused chain v2: wave-owns-row halo version (proven ~109us) ===
__global__ __launch_bounds__(512, 2) void k_chain(
    const int* __restrict__ tokens, const float* __restrict__ table,
    const float* __restrict__ angles, const float* __restrict__ scales,
    const float* __restrict__ shifts, const float* __restrict__ normw,
    const float* __restrict__ mixw, const float* __restrict__ outnw,
    const int* __restrict__ pi_all, const int* __restrict__ pj_all,
    const float* __restrict__ lmhead,
    unsigned short* __restrict__ xbf, unsigned short* __restrict__ wbf)
{
    __shared__ float lx[32][D_DIM];   // 128 KiB exactly
    const int blk = blockIdx.x, tid = threadIdx.x;
    const int wv = tid >> 6, ln = tid & 63;
    const int t0 = blk << 4;
    const int s0 = t0 & (S_LEN - 1);
    const int seqbase = t0 & ~(S_LEN - 1);
    const int r0 = wv << 2;                    // wave owns rows r0..r0+3

    const float mw0 = mixw[0], mw1 = mixw[1], mw2 = mixw[2];

    bool valid[4];
    #pragma unroll
    for (int i = 0; i < 4; ++i) {
        const int r = r0 + i;
        const int s = s0 - 8 + r;
        valid[i] = (s >= 0) && (s < S_LEN);
        float4 v0 = make_float4(0.f,0.f,0.f,0.f), v1 = v0, v2 = v0, v3 = v0;
        if (valid[i]) {
            const float* tr = table + (size_t)tokens[seqbase + s] * D_DIM;
            v0 = *(const float4*)(tr +   0 + ln * 4);
            v1 = *(const float4*)(tr + 256 + ln * 4);
            v2 = *(const float4*)(tr + 512 + ln * 4);
            v3 = *(const float4*)(tr + 768 + ln * 4);
        }
        *(float4*)&lx[r][  0 + ln * 4] = v0;
        *(float4*)&lx[r][256 + ln * 4] = v1;
        *(float4*)&lx[r][512 + ln * 4] = v2;
        *(float4*)&lx[r][768 + ln * 4] = v3;
    }
    __syncthreads();

    float4 mreg[4][4];

    for (int c = 0; c < NCYC; ++c) {
        float4 sc[4], sh[4], nw[4];
        #pragma unroll
        for (int q = 0; q < 4; ++q) {
            sc[q] = *(const float4*)(scales + c * D_DIM + q * 256 + ln * 4);
            sh[q] = *(const float4*)(shifts + c * D_DIM + q * 256 + ln * 4);
            nw[q] = *(const float4*)(normw  + c * D_DIM + q * 256 + ln * 4);
        }
        int ip[4], jp[4];
        float sa[4], ca[4];
        #pragma unroll
        for (int u = 0; u < 4; ++u) {
            ip[u] = pi_all[c * NPLANES + ln * 4 + u];
            jp[u] = pj_all[c * NPLANES + ln * 4 + u];
            sincosf(angles[c * NPLANES + ln * 4 + u], &sa[u], &ca[u]);
        }

        #pragma unroll
        for (int i = 0; i < 4; ++i) {
            const int r = r0 + i;
            if (r >= c + 1 && r < 31 - c && valid[i]) {
                #pragma unroll
                for (int q = 0; q < 4; ++q) {
                    const float4 a = *(const float4*)&lx[r - 1][q * 256 + ln * 4];
                    const float4 b = *(const float4*)&lx[r    ][q * 256 + ln * 4];
                    const float4 d = *(const float4*)&lx[r + 1][q * 256 + ln * 4];
                    mreg[i][q].x = mw0 * a.x + mw1 * b.x + mw2 * d.x;
                    mreg[i][q].y = mw0 * a.y + mw1 * b.y + mw2 * d.y;
                    mreg[i][q].z = mw0 * a.z + mw1 * b.z + mw2 * d.z;
                    mreg[i][q].w = mw0 * a.w + mw1 * b.w + mw2 * d.w;
                }
            }
        }
        __syncthreads();
        #pragma unroll
        for (int i = 0; i < 4; ++i) {
            const int r = r0 + i;
            if (r >= c + 1 && r < 31 - c && valid[i]) {
                #pragma unroll
                for (int q = 0; q < 4; ++q)
                    *(float4*)&lx[r][q * 256 + ln * 4] = mreg[i][q];
            }
        }
        #pragma unroll
        for (int i = 0; i < 4; ++i) {
            const int r = r0 + i;
            if (r >= c + 1 && r < 31 - c && valid[i]) {
                float xi[4], xj[4];
                #pragma unroll
                for (int u = 0; u < 4; ++u) { xi[u] = lx[r][ip[u]]; xj[u] = lx[r][jp[u]]; }
                #pragma unroll
                for (int u = 0; u < 4; ++u) {
                    lx[r][ip[u]] = xi[u] * ca[u] - xj[u] * sa[u];
                    lx[r][jp[u]] = xi[u] * sa[u] + xj[u] * ca[u];
                }
            }
        }
        #pragma unroll
        for (int i = 0; i < 4; ++i) {
            const int r = r0 + i;
            if (r >= c + 1 && r < 31 - c && valid[i]) {
                float4 rr[4];
                float sum = 0.f;
                #pragma unroll
                for (int q = 0; q < 4; ++q) {
                    const float4 xn = *(const float4*)&lx[r][q * 256 + ln * 4];
                    const float a0 = xn.x * sc[q].x + sh[q].x;
                    const float a1 = xn.y * sc[q].y + sh[q].y;
                    const float a2 = xn.z * sc[q].z + sh[q].z;
                    const float a3 = xn.w * sc[q].w + sh[q].w;
                    rr[q].x = a0 / (1.f + expf(-a0)) - mreg[i][q].x;
                    rr[q].y = a1 / (1.f + expf(-a1)) - mreg[i][q].y;
                    rr[q].z = a2 / (1.f + expf(-a2)) - mreg[i][q].z;
                    rr[q].w = a3 / (1.f + expf(-a3)) - mreg[i][q].w;
                    sum += rr[q].x * rr[q].x + rr[q].y * rr[q].y
                         + rr[q].z * rr[q].z + rr[q].w * rr[q].w;
                }
                #pragma unroll
                for (int off = 32; off > 0; off >>= 1)
                    sum += __shfl_xor(sum, off, 64);
                const float inv = rsqrtf(sum * (1.0f / D_DIM) + EPS_F);
                #pragma unroll
                for (int q = 0; q < 4; ++q) {
                    float4 o;
                    o.x = mreg[i][q].x + rr[q].x * inv * nw[q].x;
                    o.y = mreg[i][q].y + rr[q].y * inv * nw[q].y;
                    o.z = mreg[i][q].z + rr[q].z * inv * nw[q].z;
                    o.w = mreg[i][q].w + rr[q].w * inv * nw[q].w;
                    *(float4*)&lx[r][q * 256 + ln * 4] = o;
                }
            }
        }
        {
            const int end = (c + 1) * 1024000;
            for (int idx = c * 1024000 + blk * 512 + tid; idx < end; idx += 131072) {
                const float4 v = ((const float4*)lmhead)[idx];
                const ushort4 o = make_ushort4(f32_to_bf16(v.x), f32_to_bf16(v.y),
                                               f32_to_bf16(v.z), f32_to_bf16(v.w));
                ((ushort4*)wbf)[idx] = o;
            }
        }
        __syncthreads();
    }

    float4 ow[4];
    #pragma unroll
    for (int q = 0; q < 4; ++q)
        ow[q] = *(const float4*)(outnw + q * 256 + ln * 4);
    #pragma unroll
    for (int e = 0; e < 2; ++e) {
        const int r = 8 + wv + e * 8;
        float4 v[4];
        float sum = 0.f;
        #pragma unroll
        for (int q = 0; q < 4; ++q) {
            v[q] = *(const float4*)&lx[r][q * 256 + ln * 4];
            sum += v[q].x * v[q].x + v[q].y * v[q].y
                 + v[q].z * v[q].z + v[q].w * v[q].w;
        }
        #pragma unroll
        for (int off = 32; off > 0; off >>= 1)
            sum += __shfl_xor(sum, off, 64);
        const float inv = rsqrtf(sum * (1.0f / D_DIM) + EPS_F);
        unsigned short* xr = xbf + (size_t)(t0 + r - 8) * D_DIM;
        #pragma unroll
        for (int q = 0; q < 4; ++q) {
            const ushort4 o = make_ushort4(f32_to_bf16(v[q].x * inv * ow[q].x),
                                           f32_to_bf16(v[q].y * inv * ow[q].y),
                                           f32_to_bf16(v[q].z * inv * ow[q].z),
                                           f32_to_bf16(v[q].w * inv * ow[q].w));
            *(ushort4*)(xr + q * 256 + ln * 4) = o;
        }
    }
}

// ====== persistent GEMM: swapped operands + coalesced PLAIN dwordx4 ========
// R15 minus nontemporal. Swap keeps: (a) epilogue = 32 dwordx4/lane (4x
// fewer vmcnt-FIFO entries ahead of next tile's phase-4/8 waits), (b) the
// FETCH reduction (390->~300 MB). Plain stores restore L2 write-merging:
// consecutive ni iterations fill 256 B/row segments -> WRITE back to ~512 MB
// (R15's nt emitted unmerged 64 B bursts -> 745 MB, +65us of HBM write).
#define GLD_LDS(g, l)                                                          \
    __builtin_amdgcn_global_load_lds(                                          \
        (const __attribute__((address_space(1))) void*)(g),                    \
        (__attribute__((address_space(3))) void*)(l), 16, 0, 0)

#define STAGE_A(BUF, H, KT, P) do {                                            \
    GLD_LDS((P) + (size_t)(H) * 131072 + (size_t)(KT) * 64,                    \
            &lds[(BUF) * 32768 + (H) * 8192 + wave * 1024]);                   \
    GLD_LDS((P) + (size_t)(H) * 131072 + 8192 + (size_t)(KT) * 64,             \
            &lds[(BUF) * 32768 + (H) * 8192 + wave * 1024 + 512]);             \
} while (0)

#define STAGE_B(BUF, H, KT, P) do {                                            \
    GLD_LDS((P) + (size_t)(H) * 131072 + (size_t)(KT) * 64,                    \
            &lds[16384 + (BUF) * 32768 + (H) * 8192 + wave * 1024]);           \
    GLD_LDS((P) + (size_t)(H) * 131072 + 8192 + (size_t)(KT) * 64,             \
            &lds[16384 + (BUF) * 32768 + (H) * 8192 + wave * 1024 + 512]);     \
} while (0)

#define RD_A(BUF, MIB) do { _Pragma("unroll")                                  \
    for (int q_ = 0; q_ < 4; ++q_) {                                           \
        afr[q_][0] = *(const bf16x8*)&lds[(BUF) * 32768 + aoff + ((MIB) + q_) * 1024 + kx0]; \
        afr[q_][1] = *(const bf16x8*)&lds[(BUF) * 32768 + aoff + ((MIB) + q_) * 1024 + kx1]; \
    } } while (0)

#define RD_B(BUF, NIB, DST) do { _Pragma("unroll")                             \
    for (int n_ = 0; n_ < 2; ++n_) {                                           \
        DST[n_][0] = *(const bf16x8*)&lds[(BUF) * 32768 + boff + ((NIB) + n_) * 1024 + kx0]; \
        DST[n_][1] = *(const bf16x8*)&lds[(BUF) * 32768 + boff + ((NIB) + n_) * 1024 + kx1]; \
    } } while (0)

// swapped operand order: D^T layout -> lane regs = consecutive N cols
#define MFMA16(MIB, NIB, BF) do {                                              \
    __builtin_amdgcn_s_setprio(1);                                             \
    _Pragma("unroll") for (int m_ = 0; m_ < 4; ++m_)                           \
    _Pragma("unroll") for (int n_ = 0; n_ < 2; ++n_) {                         \
        acc[(MIB) + m_][(NIB) + n_] = __builtin_amdgcn_mfma_f32_16x16x32_bf16( \
            BF[n_][0], afr[m_][0], acc[(MIB) + m_][(NIB) + n_], 0, 0, 0);      \
        acc[(MIB) + m_][(NIB) + n_] = __builtin_amdgcn_mfma_f32_16x16x32_bf16( \
            BF[n_][1], afr[m_][1], acc[(MIB) + m_][(NIB) + n_], 0, 0, 0);      \
    }                                                                          \
    __builtin_amdgcn_s_setprio(0); } while (0)

#define PH_SYNC() do { asm volatile("" ::: "memory");                          \
    __builtin_amdgcn_s_barrier();                                              \
    asm volatile("" ::: "memory"); } while (0)
#define PH_END() do { asm volatile("" ::: "memory");                           \
    __builtin_amdgcn_s_barrier(); } while (0)
#define VMCNT4() asm volatile("s_waitcnt vmcnt(4)" ::: "memory")

__global__ __launch_bounds__(512, 2) void k_gemm(
    const unsigned short* __restrict__ A,   // [NTOK, 1024] bf16 bits
    const unsigned short* __restrict__ Bw,  // [V, 1024]    bf16 bits
    float* __restrict__ C)                  // [NTOK, V]    fp32
{
    __shared__ __align__(16) unsigned short lds[65536];   // 128 KiB
    const int tid = threadIdx.x;
    const int wave = tid >> 6, lane = tid & 63;
    const int wm = wave >> 2, wn = wave & 3;
    const int lr = lane & 15, kg = lane >> 4;

    const int xr  = (lane & 7) * 8;
    const int kx0 = (kg * 8) ^ xr;
    const int kx1 = (32 + kg * 8) ^ xr;
    const int aoff = (wm * 128 + lr) * 64;
    const int boff = 16384 + (wn * 64 + lr) * 64;

    const int srow = lane >> 3;
    const int scol = ((lane & 7) ^ srow) * 8;   // pre-swizzled source col
    const int soff = (wave * 16 + srow) * 1024 + scol;

    const int xcd = blockIdx.x & 7;
    const int rr  = blockIdx.x >> 3;            // 0..31
    const int tbase = xcd * 250 + rr * 8;
    const int ntile_mine = (rr == 31) ? 2 : 8;  // 31*8+2 = 250 per XCD

    int T  = tbase;
    int bm = T & 15, bn = T >> 4;
    const unsigned short* gA = A  + (size_t)(bm * 256) * 1024 + soff;
    const unsigned short* gB = Bw + (size_t)(bn * 256) * 1024 + soff;

    bf16x8 afr[4][2], b01[2][2], b23[2][2];

    STAGE_A(0, 0, 0, gA); STAGE_A(0, 1, 0, gA);
    STAGE_B(0, 0, 0, gB); STAGE_B(0, 1, 0, gB);
    STAGE_B(1, 0, 1, gB); STAGE_B(1, 1, 1, gB);
    VMCNT4();
    __builtin_amdgcn_s_barrier();

    for (int t = 0; t < ntile_mine; ++t) {
        const bool last = (t == ntile_mine - 1);
        const int Tn = last ? T : T + 1;
        const int bm2 = Tn & 15, bn2 = Tn >> 4;
        const unsigned short* gA2 = A  + (size_t)(bm2 * 256) * 1024 + soff;
        const unsigned short* gB2 = Bw + (size_t)(bn2 * 256) * 1024 + soff;

        f32x4 acc[8][4];
        #pragma unroll
        for (int i = 0; i < 8; ++i)
            #pragma unroll
            for (int j2 = 0; j2 < 4; ++j2) acc[i][j2] = (f32x4){0.f, 0.f, 0.f, 0.f};

        for (int j = 0; j < 8; ++j) {
            const unsigned short* sA = (j == 7) ? gA2 : gA;
            const unsigned short* sB = (j == 7) ? gB2 : gB;
            const int k1 = 2 * j + 1;
            const int k2 = (2 * j + 2) & 15;
            const int k3 = (2 * j + 3) & 15;

            RD_A(0, 0); RD_B(0, 0, b01);
            STAGE_A(1, 0, k1, gA);
            PH_SYNC(); MFMA16(0, 0, b01); PH_END();

            RD_B(0, 2, b23);
            STAGE_A(1, 1, k1, gA);
            PH_SYNC(); MFMA16(0, 2, b23); PH_END();

            RD_A(0, 4);
            STAGE_B(0, 0, k2, sB);
            PH_SYNC(); MFMA16(4, 2, b23); PH_END();

            STAGE_B(0, 1, k2, sB);
            VMCNT4();
            PH_SYNC(); MFMA16(4, 0, b01); PH_END();

            RD_A(1, 0); RD_B(1, 0, b01);
            STAGE_A(0, 0, k2, sA);
            PH_SYNC(); MFMA16(0, 0, b01); PH_END();

            RD_B(1, 2, b23);
            STAGE_A(0, 1, k2, sA);
            PH_SYNC(); MFMA16(0, 2, b23); PH_END();

            RD_A(1, 4);
            STAGE_B(1, 0, k3, sB);
            PH_SYNC(); MFMA16(4, 2, b23); PH_END();

            STAGE_B(1, 1, k3, sB);
            VMCNT4();
            PH_SYNC(); MFMA16(4, 0, b01); PH_END();
        }

        // epilogue (swapped layout): M = lr, N = kg*4 + reg.
        // Lane stores acc[mi][ni] as ONE dwordx4 at row mi*16+lr,
        // cols ni*16+kg*4..+3 -- plain stores, L2-merged into 256 B rows.
        #pragma unroll
        for (int mi = 0; mi < 8; ++mi) {
            const size_t m = (size_t)(bm * 256 + wm * 128 + mi * 16 + lr);
            #pragma unroll
            for (int ni = 0; ni < 4; ++ni) {
                const int n = bn * 256 + wn * 64 + ni * 16 + kg * 4;
                *(f32x4*)(C + m * V_DIM + n) = acc[mi][ni];
            }
        }

        T = Tn; bm = bm2; bn = bn2; gA = gA2; gB = gB2;
    }
}

extern "C" void kernel_launch(void* const* d_in, const int* in_sizes, int n_in,
                              void* d_out, int out_size, void* d_ws, size_t ws_size,
                              hipStream_t stream)
{
    const int*   tokens = (const int*)  d_in[0];
    const float* embedw = (const float*)d_in[1];
    const float* angles = (const float*)d_in[2];
    const float* scales = (const float*)d_in[3];
    const float* shifts = (const float*)d_in[4];
    const float* normw  = (const float*)d_in[5];
    const float* mixw   = (const float*)d_in[6];
    const float* outnw  = (const float*)d_in[7];
    const float* lmhead = (const float*)d_in[8];
    const int*   pi_all = (const int*)  d_in[9];
    const int*   pj_all = (const int*)  d_in[10];
    float* out = (float*)d_out;

    unsigned short* xbf = (unsigned short*)d_ws;               // 8.39 MB
    unsigned short* wbf = xbf + (size_t)NTOK * D_DIM;          // 65.54 MB

    k_chain<<<NTOK / 16, 512, 0, stream>>>(tokens, embedw, angles, scales,
        shifts, normw, mixw, outnw, pi_all, pj_all, lmhead, xbf, wbf);

    k_gemm<<<256, 512, 0, stream>>>(xbf, wbf, out);
}

// Round 17
// 394.098 us; speedup vs baseline: 1.0638x; 1.0638x over previous
//
#include <hip/hip_runtime.h>

#define B_SZ   2
#define S_LEN  2048
#define D_DIM  1024
#define V_DIM  32000
#define NTOK   (B_SZ * S_LEN)   // 4096
#define NCYC   8
#define NPLANES 256
#define EPS_F  1.1920929e-07f

typedef float  f32x4  __attribute__((ext_vector_type(4)));
typedef __bf16 bf16x8 __attribute__((ext_vector_type(8)));

__device__ __forceinline__ unsigned short f32_to_bf16(float f) {
    unsigned int u = __builtin_bit_cast(unsigned int, f);
    u += 0x7fffu + ((u >> 16) & 1u);   // round-to-nearest-even
    return (unsigned short)(u >> 16);
}

// ============ fused chain: wave-owns-row halo version (proven ~105us) ======
// 256 blocks x 512 thr (8 waves). Block owns tokens [t0,t0+16) + 8-halo each
// side = 32 rows in LDS; 8 cycles run locally (valid range shrinks 1/side
// per cycle); wave w owns rows 4w..4w+3 -> row RMSNorm = wave-internal
// shfl_xor, 2 barriers/cycle. lm_head fp32->bf16 sliced across cycles.
__global__ __launch_bounds__(512, 2) void k_chain(
    const int* __restrict__ tokens, const float* __restrict__ table,
    const float* __restrict__ angles, const float* __restrict__ scales,
    const float* __restrict__ shifts, const float* __restrict__ normw,
    const float* __restrict__ mixw, const float* __restrict__ outnw,
    const int* __restrict__ pi_all, const int* __restrict__ pj_all,
    const float* __restrict__ lmhead,
    unsigned short* __restrict__ xbf, unsigned short* __restrict__ wbf)
{
    __shared__ float lx[32][D_DIM];   // 128 KiB exactly
    const int blk = blockIdx.x, tid = threadIdx.x;
    const int wv = tid >> 6, ln = tid & 63;
    const int t0 = blk << 4;
    const int s0 = t0 & (S_LEN - 1);
    const int seqbase = t0 & ~(S_LEN - 1);
    const int r0 = wv << 2;                    // wave owns rows r0..r0+3

    const float mw0 = mixw[0], mw1 = mixw[1], mw2 = mixw[2];

    bool valid[4];
    #pragma unroll
    for (int i = 0; i < 4; ++i) {
        const int r = r0 + i;
        const int s = s0 - 8 + r;
        valid[i] = (s >= 0) && (s < S_LEN);
        float4 v0 = make_float4(0.f,0.f,0.f,0.f), v1 = v0, v2 = v0, v3 = v0;
        if (valid[i]) {
            const float* tr = table + (size_t)tokens[seqbase + s] * D_DIM;
            v0 = *(const float4*)(tr +   0 + ln * 4);
            v1 = *(const float4*)(tr + 256 + ln * 4);
            v2 = *(const float4*)(tr + 512 + ln * 4);
            v3 = *(const float4*)(tr + 768 + ln * 4);
        }
        *(float4*)&lx[r][  0 + ln * 4] = v0;
        *(float4*)&lx[r][256 + ln * 4] = v1;
        *(float4*)&lx[r][512 + ln * 4] = v2;
        *(float4*)&lx[r][768 + ln * 4] = v3;
    }
    __syncthreads();

    float4 mreg[4][4];

    for (int c = 0; c < NCYC; ++c) {
        float4 sc[4], sh[4], nw[4];
        #pragma unroll
        for (int q = 0; q < 4; ++q) {
            sc[q] = *(const float4*)(scales + c * D_DIM + q * 256 + ln * 4);
            sh[q] = *(const float4*)(shifts + c * D_DIM + q * 256 + ln * 4);
            nw[q] = *(const float4*)(normw  + c * D_DIM + q * 256 + ln * 4);
        }
        int ip[4], jp[4];
        float sa[4], ca[4];
        #pragma unroll
        for (int u = 0; u < 4; ++u) {
            ip[u] = pi_all[c * NPLANES + ln * 4 + u];
            jp[u] = pj_all[c * NPLANES + ln * 4 + u];
            sincosf(angles[c * NPLANES + ln * 4 + u], &sa[u], &ca[u]);
        }

        #pragma unroll
        for (int i = 0; i < 4; ++i) {
            const int r = r0 + i;
            if (r >= c + 1 && r < 31 - c && valid[i]) {
                #pragma unroll
                for (int q = 0; q < 4; ++q) {
                    const float4 a = *(const float4*)&lx[r - 1][q * 256 + ln * 4];
                    const float4 b = *(const float4*)&lx[r    ][q * 256 + ln * 4];
                    const float4 d = *(const float4*)&lx[r + 1][q * 256 + ln * 4];
                    mreg[i][q].x = mw0 * a.x + mw1 * b.x + mw2 * d.x;
                    mreg[i][q].y = mw0 * a.y + mw1 * b.y + mw2 * d.y;
                    mreg[i][q].z = mw0 * a.z + mw1 * b.z + mw2 * d.z;
                    mreg[i][q].w = mw0 * a.w + mw1 * b.w + mw2 * d.w;
                }
            }
        }
        __syncthreads();
        #pragma unroll
        for (int i = 0; i < 4; ++i) {
            const int r = r0 + i;
            if (r >= c + 1 && r < 31 - c && valid[i]) {
                #pragma unroll
                for (int q = 0; q < 4; ++q)
                    *(float4*)&lx[r][q * 256 + ln * 4] = mreg[i][q];
            }
        }
        #pragma unroll
        for (int i = 0; i < 4; ++i) {
            const int r = r0 + i;
            if (r >= c + 1 && r < 31 - c && valid[i]) {
                float xi[4], xj[4];
                #pragma unroll
                for (int u = 0; u < 4; ++u) { xi[u] = lx[r][ip[u]]; xj[u] = lx[r][jp[u]]; }
                #pragma unroll
                for (int u = 0; u < 4; ++u) {
                    lx[r][ip[u]] = xi[u] * ca[u] - xj[u] * sa[u];
                    lx[r][jp[u]] = xi[u] * sa[u] + xj[u] * ca[u];
                }
            }
        }
        #pragma unroll
        for (int i = 0; i < 4; ++i) {
            const int r = r0 + i;
            if (r >= c + 1 && r < 31 - c && valid[i]) {
                float4 rr[4];
                float sum = 0.f;
                #pragma unroll
                for (int q = 0; q < 4; ++q) {
                    const float4 xn = *(const float4*)&lx[r][q * 256 + ln * 4];
                    const float a0 = xn.x * sc[q].x + sh[q].x;
                    const float a1 = xn.y * sc[q].y + sh[q].y;
                    const float a2 = xn.z * sc[q].z + sh[q].z;
                    const float a3 = xn.w * sc[q].w + sh[q].w;
                    rr[q].x = a0 / (1.f + expf(-a0)) - mreg[i][q].x;
                    rr[q].y = a1 / (1.f + expf(-a1)) - mreg[i][q].y;
                    rr[q].z = a2 / (1.f + expf(-a2)) - mreg[i][q].z;
                    rr[q].w = a3 / (1.f + expf(-a3)) - mreg[i][q].w;
                    sum += rr[q].x * rr[q].x + rr[q].y * rr[q].y
                         + rr[q].z * rr[q].z + rr[q].w * rr[q].w;
                }
                #pragma unroll
                for (int off = 32; off > 0; off >>= 1)
                    sum += __shfl_xor(sum, off, 64);
                const float inv = rsqrtf(sum * (1.0f / D_DIM) + EPS_F);
                #pragma unroll
                for (int q = 0; q < 4; ++q) {
                    float4 o;
                    o.x = mreg[i][q].x + rr[q].x * inv * nw[q].x;
                    o.y = mreg[i][q].y + rr[q].y * inv * nw[q].y;
                    o.z = mreg[i][q].z + rr[q].z * inv * nw[q].z;
                    o.w = mreg[i][q].w + rr[q].w * inv * nw[q].w;
                    *(float4*)&lx[r][q * 256 + ln * 4] = o;
                }
            }
        }
        {
            const int end = (c + 1) * 1024000;
            for (int idx = c * 1024000 + blk * 512 + tid; idx < end; idx += 131072) {
                const float4 v = ((const float4*)lmhead)[idx];
                const ushort4 o = make_ushort4(f32_to_bf16(v.x), f32_to_bf16(v.y),
                                               f32_to_bf16(v.z), f32_to_bf16(v.w));
                ((ushort4*)wbf)[idx] = o;
            }
        }
        __syncthreads();
    }

    float4 ow[4];
    #pragma unroll
    for (int q = 0; q < 4; ++q)
        ow[q] = *(const float4*)(outnw + q * 256 + ln * 4);
    #pragma unroll
    for (int e = 0; e < 2; ++e) {
        const int r = 8 + wv + e * 8;
        float4 v[4];
        float sum = 0.f;
        #pragma unroll
        for (int q = 0; q < 4; ++q) {
            v[q] = *(const float4*)&lx[r][q * 256 + ln * 4];
            sum += v[q].x * v[q].x + v[q].y * v[q].y
                 + v[q].z * v[q].z + v[q].w * v[q].w;
        }
        #pragma unroll
        for (int off = 32; off > 0; off >>= 1)
            sum += __shfl_xor(sum, off, 64);
        const float inv = rsqrtf(sum * (1.0f / D_DIM) + EPS_F);
        unsigned short* xr = xbf + (size_t)(t0 + r - 8) * D_DIM;
        #pragma unroll
        for (int q = 0; q < 4; ++q) {
            const ushort4 o = make_ushort4(f32_to_bf16(v[q].x * inv * ow[q].x),
                                           f32_to_bf16(v[q].y * inv * ow[q].y),
                                           f32_to_bf16(v[q].z * inv * ow[q].z),
                                           f32_to_bf16(v[q].w * inv * ow[q].w));
            *(ushort4*)(xr + q * 256 + ln * 4) = o;
        }
    }
}

// ====== persistent GEMM (R11, best measured ~293us): 256x256, BK=64, ======
// 8-phase, fence-only barriers (no blanket lgkmcnt drain -- compiler emits
// counted waits), XCD-grouped persistent tiles, cross-tile seam at j==7,
// XOR-swizzled LDS (conflict-free), plain scalar-dword epilogue (L2-merged).
#define GLD_LDS(g, l)                                                          \
    __builtin_amdgcn_global_load_lds(                                          \
        (const __attribute__((address_space(1))) void*)(g),                    \
        (__attribute__((address_space(3))) void*)(l), 16, 0, 0)

#define STAGE_A(BUF, H, KT, P) do {                                            \
    GLD_LDS((P) + (size_t)(H) * 131072 + (size_t)(KT) * 64,                    \
            &lds[(BUF) * 32768 + (H) * 8192 + wave * 1024]);                   \
    GLD_LDS((P) + (size_t)(H) * 131072 + 8192 + (size_t)(KT) * 64,             \
            &lds[(BUF) * 32768 + (H) * 8192 + wave * 1024 + 512]);             \
} while (0)

#define STAGE_B(BUF, H, KT, P) do {                                            \
    GLD_LDS((P) + (size_t)(H) * 131072 + (size_t)(KT) * 64,                    \
            &lds[16384 + (BUF) * 32768 + (H) * 8192 + wave * 1024]);           \
    GLD_LDS((P) + (size_t)(H) * 131072 + 8192 + (size_t)(KT) * 64,             \
            &lds[16384 + (BUF) * 32768 + (H) * 8192 + wave * 1024 + 512]);     \
} while (0)

#define RD_A(BUF, MIB) do { _Pragma("unroll")                                  \
    for (int q_ = 0; q_ < 4; ++q_) {                                           \
        afr[q_][0] = *(const bf16x8*)&lds[(BUF) * 32768 + aoff + ((MIB) + q_) * 1024 + kx0]; \
        afr[q_][1] = *(const bf16x8*)&lds[(BUF) * 32768 + aoff + ((MIB) + q_) * 1024 + kx1]; \
    } } while (0)

#define RD_B(BUF, NIB, DST) do { _Pragma("unroll")                             \
    for (int n_ = 0; n_ < 2; ++n_) {                                           \
        DST[n_][0] = *(const bf16x8*)&lds[(BUF) * 32768 + boff + ((NIB) + n_) * 1024 + kx0]; \
        DST[n_][1] = *(const bf16x8*)&lds[(BUF) * 32768 + boff + ((NIB) + n_) * 1024 + kx1]; \
    } } while (0)

#define MFMA16(MIB, NIB, BF) do {                                              \
    __builtin_amdgcn_s_setprio(1);                                             \
    _Pragma("unroll") for (int m_ = 0; m_ < 4; ++m_)                           \
    _Pragma("unroll") for (int n_ = 0; n_ < 2; ++n_) {                         \
        acc[(MIB) + m_][(NIB) + n_] = __builtin_amdgcn_mfma_f32_16x16x32_bf16( \
            afr[m_][0], BF[n_][0], acc[(MIB) + m_][(NIB) + n_], 0, 0, 0);      \
        acc[(MIB) + m_][(NIB) + n_] = __builtin_amdgcn_mfma_f32_16x16x32_bf16( \
            afr[m_][1], BF[n_][1], acc[(MIB) + m_][(NIB) + n_], 0, 0, 0);      \
    }                                                                          \
    __builtin_amdgcn_s_setprio(0); } while (0)

#define PH_SYNC() do { asm volatile("" ::: "memory");                          \
    __builtin_amdgcn_s_barrier();                                              \
    asm volatile("" ::: "memory"); } while (0)
#define PH_END() do { asm volatile("" ::: "memory");                           \
    __builtin_amdgcn_s_barrier(); } while (0)
#define VMCNT4() asm volatile("s_waitcnt vmcnt(4)" ::: "memory")

__global__ __launch_bounds__(512, 2) void k_gemm(
    const unsigned short* __restrict__ A,   // [NTOK, 1024] bf16 bits
    const unsigned short* __restrict__ Bw,  // [V, 1024]    bf16 bits
    float* __restrict__ C)                  // [NTOK, V]    fp32
{
    __shared__ __align__(16) unsigned short lds[65536];   // 128 KiB
    const int tid = threadIdx.x;
    const int wave = tid >> 6, lane = tid & 63;
    const int wm = wave >> 2, wn = wave & 3;
    const int lr = lane & 15, kg = lane >> 4;

    const int xr  = (lane & 7) * 8;
    const int kx0 = (kg * 8) ^ xr;
    const int kx1 = (32 + kg * 8) ^ xr;
    const int aoff = (wm * 128 + lr) * 64;
    const int boff = 16384 + (wn * 64 + lr) * 64;

    const int srow = lane >> 3;
    const int scol = ((lane & 7) ^ srow) * 8;   // pre-swizzled source col
    const int soff = (wave * 16 + srow) * 1024 + scol;

    const int xcd = blockIdx.x & 7;
    const int rr  = blockIdx.x >> 3;            // 0..31
    const int tbase = xcd * 250 + rr * 8;
    const int ntile_mine = (rr == 31) ? 2 : 8;  // 31*8+2 = 250 per XCD

    int T  = tbase;
    int bm = T & 15, bn = T >> 4;
    const unsigned short* gA = A  + (size_t)(bm * 256) * 1024 + soff;
    const unsigned short* gB = Bw + (size_t)(bn * 256) * 1024 + soff;

    bf16x8 afr[4][2], b01[2][2], b23[2][2];

    STAGE_A(0, 0, 0, gA); STAGE_A(0, 1, 0, gA);
    STAGE_B(0, 0, 0, gB); STAGE_B(0, 1, 0, gB);
    STAGE_B(1, 0, 1, gB); STAGE_B(1, 1, 1, gB);
    VMCNT4();
    __builtin_amdgcn_s_barrier();

    for (int t = 0; t < ntile_mine; ++t) {
        const bool last = (t == ntile_mine - 1);
        const int Tn = last ? T : T + 1;
        const int bm2 = Tn & 15, bn2 = Tn >> 4;
        const unsigned short* gA2 = A  + (size_t)(bm2 * 256) * 1024 + soff;
        const unsigned short* gB2 = Bw + (size_t)(bn2 * 256) * 1024 + soff;

        f32x4 acc[8][4];
        #pragma unroll
        for (int i = 0; i < 8; ++i)
            #pragma unroll
            for (int j2 = 0; j2 < 4; ++j2) acc[i][j2] = (f32x4){0.f, 0.f, 0.f, 0.f};

        for (int j = 0; j < 8; ++j) {
            const unsigned short* sA = (j == 7) ? gA2 : gA;
            const unsigned short* sB = (j == 7) ? gB2 : gB;
            const int k1 = 2 * j + 1;
            const int k2 = (2 * j + 2) & 15;
            const int k3 = (2 * j + 3) & 15;

            RD_A(0, 0); RD_B(0, 0, b01);
            STAGE_A(1, 0, k1, gA);
            PH_SYNC(); MFMA16(0, 0, b01); PH_END();

            RD_B(0, 2, b23);
            STAGE_A(1, 1, k1, gA);
            PH_SYNC(); MFMA16(0, 2, b23); PH_END();

            RD_A(0, 4);
            STAGE_B(0, 0, k2, sB);
            PH_SYNC(); MFMA16(4, 2, b23); PH_END();

            STAGE_B(0, 1, k2, sB);
            VMCNT4();
            PH_SYNC(); MFMA16(4, 0, b01); PH_END();

            RD_A(1, 0); RD_B(1, 0, b01);
            STAGE_A(0, 0, k2, sA);
            PH_SYNC(); MFMA16(0, 0, b01); PH_END();

            RD_B(1, 2, b23);
            STAGE_A(0, 1, k2, sA);
            PH_SYNC(); MFMA16(0, 2, b23); PH_END();

            RD_A(1, 4);
            STAGE_B(1, 0, k3, sB);
            PH_SYNC(); MFMA16(4, 2, b23); PH_END();

            STAGE_B(1, 1, k3, sB);
            VMCNT4();
            PH_SYNC(); MFMA16(4, 0, b01); PH_END();
        }

        #pragma unroll
        for (int mi = 0; mi < 8; ++mi) {
            const size_t m0 = (size_t)(bm * 256 + wm * 128 + mi * 16 + kg * 4);
            #pragma unroll
            for (int ni = 0; ni < 4; ++ni) {
                const int n = bn * 256 + wn * 64 + ni * 16 + lr;
                float* cp = C + m0 * V_DIM + n;
                cp[0]                 = acc[mi][ni][0];
                cp[(size_t)V_DIM]     = acc[mi][ni][1];
                cp[(size_t)2 * V_DIM] = acc[mi][ni][2];
                cp[(size_t)3 * V_DIM] = acc[mi][ni][3];
            }
        }

        T = Tn; bm = bm2; bn = bn2; gA = gA2; gB = gB2;
    }
}

extern "C" void kernel_launch(void* const* d_in, const int* in_sizes, int n_in,
                              void* d_out, int out_size, void* d_ws, size_t ws_size,
                              hipStream_t stream)
{
    const int*   tokens = (const int*)  d_in[0];
    const float* embedw = (const float*)d_in[1];
    const float* angles = (const float*)d_in[2];
    const float* scales = (const float*)d_in[3];
    const float* shifts = (const float*)d_in[4];
    const float* normw  = (const float*)d_in[5];
    const float* mixw   = (const float*)d_in[6];
    const float* outnw  = (const float*)d_in[7];
    const float* lmhead = (const float*)d_in[8];
    const int*   pi_all = (const int*)  d_in[9];
    const int*   pj_all = (const int*)  d_in[10];
    float* out = (float*)d_out;

    unsigned short* xbf = (unsigned short*)d_ws;               // 8.39 MB
    unsigned short* wbf = xbf + (size_t)NTOK * D_DIM;          // 65.54 MB

    k_chain<<<NTOK / 16, 512, 0, stream>>>(tokens, embedw, angles, scales,
        shifts, normw, mixw, outnw, pi_all, pj_all, lmhead, xbf, wbf);

    k_gemm<<<256, 512, 0, stream>>>(xbf, wbf, out);
}